// Round 2
// baseline (65810.626 us; speedup 1.0000x reference)
//
#include <hip/hip_runtime.h>
#include <stdint.h>

typedef unsigned int u32;
typedef unsigned long long u64;
typedef unsigned short u16;

typedef __attribute__((ext_vector_type(8))) short short8;
typedef __attribute__((ext_vector_type(4))) float f32x4;

#define AT_LD32(p)    __hip_atomic_load((u32*)(p), __ATOMIC_RELAXED, __HIP_MEMORY_SCOPE_AGENT)
#define AT_ST32(p,v)  __hip_atomic_store((u32*)(p), (v), __ATOMIC_RELAXED, __HIP_MEMORY_SCOPE_AGENT)
#define AT_LD64(p)    __hip_atomic_load((u64*)(p), __ATOMIC_RELAXED, __HIP_MEMORY_SCOPE_AGENT)
#define AT_ST64(p,v)  __hip_atomic_store((u64*)(p), (v), __ATOMIC_RELAXED, __HIP_MEMORY_SCOPE_AGENT)
#define AT_ADD32(p,v) __hip_atomic_fetch_add((u32*)(p), (v), __ATOMIC_RELAXED, __HIP_MEMORY_SCOPE_AGENT)
#define AT_MAX64(p,v) __hip_atomic_fetch_max((u64*)(p), (v), __ATOMIC_RELAXED, __HIP_MEMORY_SCOPE_AGENT)

__device__ __forceinline__ float sigf(float x){ return 1.0f/(1.0f+__expf(-x)); }
__device__ __forceinline__ float tanhfast(float x){ float e=__expf(2.0f*x); return (e-1.0f)/(e+1.0f); }

// round-to-nearest-even f32->bf16 pair pack
__device__ __forceinline__ u32 pk2(float a, float b){
  u32 ua=__float_as_uint(a), ub=__float_as_uint(b);
  ua = (ua + 0x7fffu + ((ua>>16)&1u)) >> 16;
  ub = (ub + 0x7fffu + ((ub>>16)&1u)) >> 16;
  return ua | (ub<<16);
}
__device__ __forceinline__ float lo16(u32 u){ return __uint_as_float(u<<16); }
__device__ __forceinline__ float hi16(u32 u){ return __uint_as_float(u & 0xffff0000u); }

__device__ __forceinline__ f32x4 mfma16(short8 a, short8 b, f32x4 c){
  return __builtin_amdgcn_mfma_f32_16x16x32_bf16(a, b, c, 0, 0, 0);
}
union U4S8 { uint4 u; short8 s; };

// ---- 2-level grid barrier (encoder only)
__device__ __forceinline__ void gbar(u32* ctrl, volatile int* bail){
  asm volatile("s_waitcnt vmcnt(0) lgkmcnt(0)" ::: "memory");
  __syncthreads();
  if (threadIdx.x == 0){
    u32* GEN = ctrl + 9*32;
    u32 g = AT_LD32(GEN);
    int leaf = blockIdx.x & 7;
    u32 n = AT_ADD32(ctrl + leaf*32, 1u);
    if (n == 31u){
      AT_ST32(ctrl + leaf*32, 0u);
      u32 r = AT_ADD32(ctrl + 8*32, 1u);
      if (r == 7u){ AT_ST32(ctrl + 8*32, 0u); AT_ADD32(GEN, 1u); }
    }
    long lim = (*bail) ? (1L<<8) : (1L<<22);
    long c = 0;
    while (AT_LD32(GEN) == g){
      __builtin_amdgcn_s_sleep(2);
      if (++c > lim){ *bail = 1; break; }
    }
  }
  __syncthreads();
}

__global__ void init_ctrl(u32* ws0){
  // zero ctrl(0..1280) flags(2048) done(2304) keys(4096..20480)
  for (int i = threadIdx.x; i < 5120; i += 512) ws0[i] = 0u;
}

__global__ void embed_k(const int* __restrict__ x, const float* __restrict__ emb,
                        float* __restrict__ emb_x){
  int gid = blockIdx.x*256 + threadIdx.x;   // 64*32*512
  int k  = gid & 511;
  int tb = gid >> 9;
  emb_x[gid] = emb[(size_t)x[tb]*512 + k];
}

// f32 -> bf16 row convert (first 512 of srcStride cols)
__global__ void conv_bf16_k(const float* __restrict__ src, int srcStride, u16* __restrict__ dst){
  int idx = blockIdx.x*256 + threadIdx.x;   // 2560*256
  int r = idx >> 8, kp = idx & 255;
  const float* s = src + (size_t)r*srcStride + kp*2;
  ((u32*)dst)[r*256 + kp] = pk2(s[0], s[1]);
}

// C[m][n] = bias + sum_k A[m*lda+k]*B[n*ldb+boff+k]; grid=(N/256, M/8)
__global__ __launch_bounds__(256) void gemm_f32(
    const float* __restrict__ A, int lda,
    const float* __restrict__ Bm, int ldb, int boff,
    const float* __restrict__ bias, int biasOnM,
    float* __restrict__ C, int ldc, int K)
{
  __shared__ float As[8][1028];
  int n  = blockIdx.x*256 + threadIdx.x;
  int m0 = blockIdx.y*8;
  for (int idx = threadIdx.x; idx < 8*K; idx += 256){
    int mm = idx / K, kk = idx - mm*K;
    As[mm][kk] = A[(size_t)(m0+mm)*lda + kk];
  }
  __syncthreads();
  float acc[8];
  if (biasOnM){
    #pragma unroll
    for (int mm=0; mm<8; ++mm) acc[mm] = bias[m0+mm];
  } else {
    float bs = bias[n];
    #pragma unroll
    for (int mm=0; mm<8; ++mm) acc[mm] = bs;
  }
  const float* bp = Bm + (size_t)n*ldb + boff;
  for (int k = 0; k < K; k += 4){
    float4 w = *(const float4*)(bp + k);
    #pragma unroll
    for (int mm = 0; mm < 8; ++mm)
      acc[mm] += As[mm][k]*w.x + As[mm][k+1]*w.y + As[mm][k+2]*w.z + As[mm][k+3]*w.w;
  }
  #pragma unroll
  for (int mm = 0; mm < 8; ++mm)
    C[(size_t)(m0+mm)*ldc + n] = acc[mm];
}

// ---------------- persistent bidirectional encoder (round-1, unchanged) ----------------
__global__ __launch_bounds__(512) void enc_persist(
    const float* __restrict__ Whh_f, const float* __restrict__ Whh_b,
    const float* __restrict__ Gx_f,  const float* __restrict__ Gx_b,
    float* __restrict__ h_cat, u32* ctrl, u32* hbuf)
{
  __shared__ __align__(16) u32 uni[32*268];
  __shared__ __align__(16) u32 wldsb[16*256];
  __shared__ float clds[128];
  __shared__ float exch[128];
  __shared__ int bail;

  const int tid = threadIdx.x, bid = blockIdx.x;
  const int dir = bid >> 7, dblk = bid & 127, d0 = dblk*4;
  const int b = tid & 31, grp = tid >> 5;
  const int dL = grp & 3, ks = grp >> 2;
  if (tid == 0) bail = 0;

  const float* Whh = dir ? Whh_b : Whh_f;
  const float* Gx  = dir ? Gx_b  : Gx_f;

  for (int idx = tid; idx < 16*256; idx += 512){
    int r = idx >> 8, p = idx & 255;
    int g = r >> 2, dl = r & 3;
    const float* wr = Whh + (size_t)(g*512 + d0 + dl)*512 + p*2;
    wldsb[idx] = pk2(wr[0], wr[1]);
  }

  u32* hb = hbuf + dir*2*8192;

  for (int t = 0; t < 64; ++t){
    int teff = dir ? (63 - t) : t;
    if (t > 0){
      const u32* src = hb + ((t&1)<<13);
      for (int idx = tid; idx < 8192; idx += 512)
        uni[(idx&31)*268 + (idx>>5)] = AT_LD32(src + idx);
    }
    __syncthreads();
    float a0=0.f,a1=0.f,a2=0.f,a3=0.f;
    if (t > 0){
      const u32* srow = uni + b*268 + ks*64;
      for (int c4 = 0; c4 < 16; ++c4){
        uint4 s4 = *(const uint4*)(srow + c4*4);
        float f0=lo16(s4.x),f1=hi16(s4.x),f2=lo16(s4.y),f3=hi16(s4.y);
        float f4=lo16(s4.z),f5=hi16(s4.z),f6=lo16(s4.w),f7=hi16(s4.w);
        int kp = ks*64 + c4*4;
        #pragma unroll
        for (int g = 0; g < 4; ++g){
          uint4 wq = *(const uint4*)(wldsb + (g*4+dL)*256 + kp);
          float s = f0*lo16(wq.x)+f1*hi16(wq.x)+f2*lo16(wq.y)+f3*hi16(wq.y)
                  + f4*lo16(wq.z)+f5*hi16(wq.z)+f6*lo16(wq.w)+f7*hi16(wq.w);
          if (g==0) a0+=s; else if (g==1) a1+=s; else if (g==2) a2+=s; else a3+=s;
        }
      }
    }
    __syncthreads();
    float* part = (float*)uni;
    { int base=(grp*32+b)*4; part[base]=a0; part[base+1]=a1; part[base+2]=a2; part[base+3]=a3; }
    __syncthreads();
    if (tid < 128){
      int bb = tid & 31, dl = tid >> 5;
      float r0=0.f,r1=0.f,r2=0.f,r3=0.f;
      #pragma unroll
      for (int kk = 0; kk < 4; ++kk){
        const float* p4 = part + (((kk<<2)|dl)*32 + bb)*4;
        r0+=p4[0]; r1+=p4[1]; r2+=p4[2]; r3+=p4[3];
      }
      const float* gx = Gx + ((size_t)teff*32 + bb)*2048;
      int d = d0 + dl;
      float gi=r0+gx[d], gf=r1+gx[512+d], gg=r2+gx[1024+d], go=r3+gx[1536+d];
      float c_ = (t==0) ? 0.f : clds[tid];
      float cn = sigf(gf)*c_ + sigf(gi)*tanhfast(gg);
      float hn = sigf(go)*tanhfast(cn);
      clds[tid] = cn;
      exch[tid] = hn;
      h_cat[((size_t)teff*32 + bb)*1024 + dir*512 + d] = hn;
    }
    __syncthreads();
    if (tid < 64){
      int bb = tid & 31, pp = tid >> 5;
      u32 u = pk2(exch[(pp*2)*32 + bb], exch[(pp*2+1)*32 + bb]);
      AT_ST32(hb + (((t+1)&1)<<13) + (dblk*2 + pp)*32 + bb, u);
    }
    gbar(ctrl, &bail);
  }
}

// ---------------- decoder v2: 32 MFMA cell blocks + 224 logits blocks, flag-sync ----------------
union DSm {
  struct {
    u32   slds[8192];     // staged A (s or y_emb) [32][256] u32, XOR-swizzled in 16B granules
    float pre[2880];      // [c=80][36]  (c = q*16+dd)
    float ypl[2880];
    float sexch[512];
    int   tokl[32];
  } c;
  struct {
    u32   uni[8224];      // [32][257]
    float lred[4752];     // [144][33]
    u64   kred[512];      // [16][32]
  } l;
};

__device__ __forceinline__ void mfma_phase(const u32* __restrict__ sldsp,
    const u16* __restrict__ Bw, float* __restrict__ dst,
    int lane, int mtile, int nt0, int nB, int d0)
{
  const int mrow  = mtile*16 + (lane & 15);
  const int abase = mrow*256;
  const int asw   = (mrow & 7) << 2;
  const int ddc   = lane & 15;
  const size_t br0 = ((size_t)(nt0*512 + d0 + ddc)) * 512;
  const size_t br1 = ((size_t)((nt0+1)*512 + d0 + ddc)) * 512;
  const int kl = (lane >> 4) * 8;
  f32x4 acc0 = {0.f,0.f,0.f,0.f}, acc1 = {0.f,0.f,0.f,0.f};
  #pragma unroll
  for (int ks = 0; ks < 16; ++ks){
    const int dw = ks*16 + (lane>>4)*4;
    U4S8 a;  a.u  = *(const uint4*)&sldsp[abase + (dw ^ asw)];
    U4S8 b0; b0.u = *(const uint4*)(Bw + br0 + ks*32 + kl);
    acc0 = mfma16(a.s, b0.s, acc0);
    if (nB > 1){
      U4S8 b1; b1.u = *(const uint4*)(Bw + br1 + ks*32 + kl);
      acc1 = mfma16(a.s, b1.s, acc1);
    }
  }
  {
    float* p = &dst[(nt0*16 + ddc)*36 + mtile*16 + ((lane>>4)<<2)];
    *(f32x4*)p = acc0;
  }
  if (nB > 1){
    float* p = &dst[((nt0+1)*16 + ddc)*36 + mtile*16 + ((lane>>4)<<2)];
    *(f32x4*)p = acc1;
  }
}

__global__ __launch_bounds__(512) void dec_persist(
    const u16* __restrict__ Wsbf, const u16* __restrict__ Wxbf,
    const float* __restrict__ Wl, const float* __restrict__ bl,
    const float* __restrict__ emb, const float* __restrict__ hpartT,
    u32* flags, u32* done, u64* keys, u32* sbuf, float* __restrict__ out)
{
  __shared__ DSm sm;
  const int tid = threadIdx.x, bid = blockIdx.x;
  const int lane = tid & 63;

  if (bid < 32){
    // ================= cell blocks =================
    const int w = tid >> 6, mtile = w & 1, ng = w >> 1;
    const int nt0 = (ng == 0) ? 0 : (ng + 1);
    const int nB  = (ng == 0) ? 2 : 1;
    const int dd = tid >> 5, b = tid & 31;
    const int d0 = bid * 16;
    float creg = 0.f;

    for (int i = 0; i < 64; ++i){
      const u32 base = i*64;
      if (i == 0){
        for (int idx = tid; idx < 2880; idx += 512) sm.c.ypl[idx] = 0.f;
        __syncthreads();
      } else {
        if (tid < 64){
          long cc = 0;
          while (AT_LD32(done + (i-1)) < 224u){
            __builtin_amdgcn_s_sleep(4);
            if (++cc > (1L<<22)) break;
          }
        }
        __syncthreads();
        if (tid < 32){
          u64 kk = AT_LD64(keys + (size_t)(i-1)*32 + tid);
          int tk = (int)(~(u32)kk);
          tk = tk < 0 ? 0 : (tk > 31999 ? 31999 : tk);
          sm.c.tokl[tid] = tk;
        }
        __syncthreads();
        for (int idx = tid; idx < 8192; idx += 512){
          int bb = idx >> 8, dp = idx & 255;
          const float* er = emb + (size_t)sm.c.tokl[bb]*512 + dp*2;
          sm.c.slds[bb*256 + (dp ^ ((bb&7)<<2))] = pk2(er[0], er[1]);
        }
        __syncthreads();
        mfma_phase(sm.c.slds, Wxbf, sm.c.ypl, lane, mtile, nt0, nB, d0);
        __syncthreads();
      }
      creg = 0.f;

      for (int j = 0; j < 64; ++j){
        const u32 g = base + j + 1;   // state produced this step
        float hp[5];
        {
          const float* hb = hpartT + (size_t)(d0 + dd)*2048 + j*32 + b;
          #pragma unroll
          for (int q = 0; q < 5; ++q) hp[q] = hb[(size_t)q*512*2048];
        }
        if (j > 0){
          const u32 tgt = base + j;
          long cc = 0;
          for(;;){
            u32 f = (lane < 32) ? AT_LD32(flags + lane) : 0xffffffffu;
            if (__all((int)(f >= tgt))) break;
            __builtin_amdgcn_s_sleep(1);
            if (++cc > (1L<<22)) break;
          }
          const u32* sb = sbuf + ((size_t)((g-1) & 1) << 13);
          for (int idx = tid; idx < 8192; idx += 512){
            int bb = idx >> 8, dp = idx & 255;
            sm.c.slds[bb*256 + (dp ^ ((bb&7)<<2))] = AT_LD32(sb + idx);
          }
          __syncthreads();
          mfma_phase(sm.c.slds, Wsbf, sm.c.pre, lane, mtile, nt0, nB, d0);
        }
        __syncthreads();
        // gates: one thread per (dd, b)
        {
          float pv[5];
          #pragma unroll
          for (int q = 0; q < 5; ++q){
            float x = sm.c.ypl[(q*16 + dd)*36 + b] + hp[q];
            if (j > 0) x += sm.c.pre[(q*16 + dd)*36 + b];
            pv[q] = x;
          }
          float gi = sigf(pv[0]), gf = sigf(pv[1]), go = sigf(pv[2]), gl = sigf(pv[3]);
          float cn = gf * (gl * creg) + gi * tanhfast(pv[4]);
          creg = cn;
          sm.c.sexch[dd*32 + b] = go * tanhfast(cn);
        }
        __syncthreads();
        if (tid < 256){
          int d2 = tid >> 5, bb = tid & 31;
          u32 u = pk2(sm.c.sexch[(d2*2)*32 + bb], sm.c.sexch[(d2*2+1)*32 + bb]);
          AT_ST32(sbuf + ((size_t)(g & 1) << 13) + bb*256 + (d0 >> 1) + d2, u);
        }
        asm volatile("s_waitcnt vmcnt(0)" ::: "memory");
        __syncthreads();
        if (tid == 0) AT_ST32(flags + bid, g);
      }
    }
  } else {
    // ================= logits blocks =================
    const int lb = bid - 32;
    const int v0 = lb * 143;
    int nv = 32000 - v0; if (nv > 143) nv = 143;
    const int grp = tid >> 5, b = tid & 31;

    for (int i = 0; i < 64; ++i){
      const u32 tgt = (u32)i*64 + 64;
      if (tid < 64){
        long cc = 0;
        for(;;){
          u32 f = (lane < 32) ? AT_LD32(flags + lane) : 0xffffffffu;
          if (__all((int)(f >= tgt))) break;
          __builtin_amdgcn_s_sleep(6);
          if (++cc > (1L<<22)) break;
        }
      }
      __syncthreads();
      for (int idx = tid; idx < 8192; idx += 512){
        int bb = idx >> 8, dp = idx & 255;
        sm.l.uni[bb*257 + dp] = AT_LD32(sbuf + idx);   // s_J parity 0
      }
      __syncthreads();
      float acc[9];
      #pragma unroll
      for (int t = 0; t < 9; ++t){
        int vt = grp + 16*t;
        acc[t] = (vt < nv) ? bl[v0 + vt] : -1e30f;
      }
      const u32* srow = sm.l.uni + b*257;
      for (int pp = 0; pp < 128; ++pp){
        u32 u0 = srow[pp*2], u1 = srow[pp*2 + 1];
        float f0 = lo16(u0), f1 = hi16(u0), f2 = lo16(u1), f3 = hi16(u1);
        #pragma unroll
        for (int t = 0; t < 9; ++t){
          int vt = grp + 16*t;
          if (vt < nv){
            const float4 w4 = *(const float4*)(Wl + (size_t)(v0 + vt)*512 + pp*4);
            acc[t] += f0*w4.x + f1*w4.y + f2*w4.z + f3*w4.w;
          }
        }
      }
      u64 best = 0;
      #pragma unroll
      for (int t = 0; t < 9; ++t){
        int vt = grp + 16*t;
        if (vt < nv){
          sm.l.lred[vt*33 + b] = acc[t];
          u32 su = __float_as_uint(acc[t]);
          su = (su >> 31) ? ~su : (su | 0x80000000u);
          u64 key = ((u64)su << 32) | (u32)(~(u32)(v0 + vt));
          if (key > best) best = key;
        }
      }
      sm.l.kred[grp*32 + b] = best;
      __syncthreads();
      const size_t obase = ((size_t)i*32)*32000 + v0;
      for (int bb = 0; bb < 32; ++bb){
        for (int v = tid; v < nv; v += 512)
          out[obase + (size_t)bb*32000 + v] = sm.l.lred[v*33 + bb];
      }
      if (tid < 32){
        u64 m = 0;
        #pragma unroll
        for (int q2 = 0; q2 < 16; ++q2){ u64 x = sm.l.kred[q2*32 + tid]; if (x > m) m = x; }
        AT_MAX64(keys + (size_t)i*32 + tid, m);
      }
      asm volatile("s_waitcnt vmcnt(0)" ::: "memory");
      __syncthreads();
      if (tid == 0) AT_ADD32(done + i, 1u);
    }
  }
}

__global__ __launch_bounds__(256) void softmax_k(float* __restrict__ out){
  size_t row = blockIdx.x;
  float* p = out + row*32000;
  __shared__ float red[256];
  float s = 0.f;
  for (int v = threadIdx.x; v < 32000; v += 256) s += __expf(p[v]);
  red[threadIdx.x] = s;
  __syncthreads();
  for (int off = 128; off > 0; off >>= 1){
    if (threadIdx.x < off) red[threadIdx.x] += red[threadIdx.x+off];
    __syncthreads();
  }
  float Z = red[0];
  for (int v = threadIdx.x; v < 32000; v += 256) p[v] = __expf(p[v]) / Z;
}

extern "C" void kernel_launch(void* const* d_in, const int* in_sizes, int n_in,
                              void* d_out, int out_size, void* d_ws, size_t ws_size,
                              hipStream_t stream)
{
  const int*   x    = (const int*)d_in[0];
  const float* emb  = (const float*)d_in[2];
  const float* Wihf = (const float*)d_in[3];
  const float* Whhf = (const float*)d_in[4];
  const float* bf   = (const float*)d_in[5];
  const float* Wihb = (const float*)d_in[6];
  const float* Whhb = (const float*)d_in[7];
  const float* bb   = (const float*)d_in[8];
  const float* Wx   = (const float*)d_in[9];
  const float* Ws   = (const float*)d_in[10];
  const float* bc   = (const float*)d_in[11];
  const float* Wl   = (const float*)d_in[12];
  const float* bl   = (const float*)d_in[13];

  char* ws = (char*)d_ws;
  u32* ctrl   = (u32*)ws;                       // 1280 B (gbar)
  u32* flags  = (u32*)(ws + 2048);              // 32 u32
  u32* done   = (u32*)(ws + 2304);              // 64 u32
  u64* keys   = (u64*)(ws + 4096);              // 64x32 u64 = 16 KB
  u32* sbuf   = (u32*)(ws + 20480);             // 2x8192 u32 = 64 KB
  u32* hbuf   = (u32*)(ws + 86016);             // 128 KB -> 217088
  float* emb_x = (float*)(ws + 217088);         // 4 MB   -> 4411392
  float* h_cat = (float*)(ws + 4411392);        // 8 MB   -> 12800000
  float* GxfP  = (float*)(ws + 12800000);       // 16 MB  -> 29577216
  float* GxbP  = (float*)(ws + 29577216);       // 16 MB  -> 46354432
  float* hpartT = GxfP;                         // 2560x2048 f32 = 21 MB (Gx dead after encoder)
  u16* Wsbf = (u16*)emb_x;                      // 2.6 MB (emb_x dead after Gx gemms)
  u16* Wxbf = (u16*)h_cat;                      // 2.6 MB (h_cat dead after hpartT gemm)

  hipLaunchKernelGGL(init_ctrl, dim3(1), dim3(512), 0, stream, (u32*)ws);
  hipLaunchKernelGGL(embed_k, dim3(4096), dim3(256), 0, stream, x, emb, emb_x);
  hipLaunchKernelGGL(gemm_f32, dim3(8,256), dim3(256), 0, stream,
                     emb_x, 512, Wihf, 512, 0, bf, 0, GxfP, 2048, 512);
  hipLaunchKernelGGL(gemm_f32, dim3(8,256), dim3(256), 0, stream,
                     emb_x, 512, Wihb, 512, 0, bb, 0, GxbP, 2048, 512);
  hipLaunchKernelGGL(enc_persist, dim3(256), dim3(512), 0, stream,
                     Whhf, Whhb, GxfP, GxbP, h_cat, ctrl, hbuf);
  // hpartT[c][t*32+b] = bc[c] + sum_k h_cat[(t*32+b)*1024+k] * Wx[c*1536 + 512 + k]
  hipLaunchKernelGGL(gemm_f32, dim3(8,320), dim3(256), 0, stream,
                     Wx + 512, 1536, h_cat, 1024, 0, bc, 1, hpartT, 2048, 1024);
  hipLaunchKernelGGL(conv_bf16_k, dim3(2560), dim3(256), 0, stream, Ws, 1024, Wsbf);
  hipLaunchKernelGGL(conv_bf16_k, dim3(2560), dim3(256), 0, stream, Wx, 1536, Wxbf);
  hipLaunchKernelGGL(dec_persist, dim3(256), dim3(512), 0, stream,
                     Wsbf, Wxbf, Wl, bl, emb, hpartT, flags, done, keys, sbuf, (float*)d_out);
  hipLaunchKernelGGL(softmax_k, dim3(2048), dim3(256), 0, stream, (float*)d_out);
}

// Round 3
// 53517.065 us; speedup vs baseline: 1.2297x; 1.2297x over previous
//
#include <hip/hip_runtime.h>
#include <stdint.h>

typedef unsigned int u32;
typedef unsigned long long u64;
typedef unsigned short u16;

typedef __attribute__((ext_vector_type(8))) short short8;
typedef __attribute__((ext_vector_type(4))) float f32x4;

#define AT_LD32(p)    __hip_atomic_load((u32*)(p), __ATOMIC_RELAXED, __HIP_MEMORY_SCOPE_AGENT)
#define AT_ST32(p,v)  __hip_atomic_store((u32*)(p), (v), __ATOMIC_RELAXED, __HIP_MEMORY_SCOPE_AGENT)
#define AT_LD64(p)    __hip_atomic_load((u64*)(p), __ATOMIC_RELAXED, __HIP_MEMORY_SCOPE_AGENT)
#define AT_ST64(p,v)  __hip_atomic_store((u64*)(p), (v), __ATOMIC_RELAXED, __HIP_MEMORY_SCOPE_AGENT)
#define AT_ADD32(p,v) __hip_atomic_fetch_add((u32*)(p), (v), __ATOMIC_RELAXED, __HIP_MEMORY_SCOPE_AGENT)
#define AT_MAX64(p,v) __hip_atomic_fetch_max((u64*)(p), (v), __ATOMIC_RELAXED, __HIP_MEMORY_SCOPE_AGENT)

__device__ __forceinline__ float sigf(float x){ return 1.0f/(1.0f+__expf(-x)); }
__device__ __forceinline__ float tanhfast(float x){ float e=__expf(2.0f*x); return (e-1.0f)/(e+1.0f); }

// round-to-nearest-even f32->bf16 pair pack
__device__ __forceinline__ u32 pk2(float a, float b){
  u32 ua=__float_as_uint(a), ub=__float_as_uint(b);
  ua = (ua + 0x7fffu + ((ua>>16)&1u)) >> 16;
  ub = (ub + 0x7fffu + ((ub>>16)&1u)) >> 16;
  return ua | (ub<<16);
}
__device__ __forceinline__ float lo16(u32 u){ return __uint_as_float(u<<16); }
__device__ __forceinline__ float hi16(u32 u){ return __uint_as_float(u & 0xffff0000u); }

__device__ __forceinline__ f32x4 mfma16(short8 a, short8 b, f32x4 c){
  return __builtin_amdgcn_mfma_f32_16x16x32_bf16(a, b, c, 0, 0, 0);
}
union U4S8 { uint4 u; short8 s; };

// ---- 2-level grid barrier (encoder only)
__device__ __forceinline__ void gbar(u32* ctrl, volatile int* bail){
  asm volatile("s_waitcnt vmcnt(0) lgkmcnt(0)" ::: "memory");
  __syncthreads();
  if (threadIdx.x == 0){
    u32* GEN = ctrl + 9*32;
    u32 g = AT_LD32(GEN);
    int leaf = blockIdx.x & 7;
    u32 n = AT_ADD32(ctrl + leaf*32, 1u);
    if (n == 31u){
      AT_ST32(ctrl + leaf*32, 0u);
      u32 r = AT_ADD32(ctrl + 8*32, 1u);
      if (r == 7u){ AT_ST32(ctrl + 8*32, 0u); AT_ADD32(GEN, 1u); }
    }
    long lim = (*bail) ? (1L<<8) : (1L<<22);
    long c = 0;
    while (AT_LD32(GEN) == g){
      __builtin_amdgcn_s_sleep(2);
      if (++c > lim){ *bail = 1; break; }
    }
  }
  __syncthreads();
}

__global__ void init_ctrl(u32* ws0){
  // zero bytes 0..24576: ctrl, stepcnt, done, rowcnt, keys
  for (int i = threadIdx.x; i < 6144; i += 512) ws0[i] = 0u;
}

__global__ void embed_k(const int* __restrict__ x, const float* __restrict__ emb,
                        float* __restrict__ emb_x){
  int gid = blockIdx.x*256 + threadIdx.x;   // 64*32*512
  int k  = gid & 511;
  int tb = gid >> 9;
  emb_x[gid] = emb[(size_t)x[tb]*512 + k];
}

// f32 -> bf16 row convert (first 512 of srcStride cols)
__global__ void conv_bf16_k(const float* __restrict__ src, int srcStride, u16* __restrict__ dst){
  int idx = blockIdx.x*256 + threadIdx.x;   // 2560*256
  int r = idx >> 8, kp = idx & 255;
  const float* s = src + (size_t)r*srcStride + kp*2;
  ((u32*)dst)[r*256 + kp] = pk2(s[0], s[1]);
}

// C[m][n] = bias + sum_k A[m*lda+k]*B[n*ldb+boff+k]; grid=(N/256, M/8)
__global__ __launch_bounds__(256) void gemm_f32(
    const float* __restrict__ A, int lda,
    const float* __restrict__ Bm, int ldb, int boff,
    const float* __restrict__ bias, int biasOnM,
    float* __restrict__ C, int ldc, int K)
{
  __shared__ float As[8][1028];
  int n  = blockIdx.x*256 + threadIdx.x;
  int m0 = blockIdx.y*8;
  for (int idx = threadIdx.x; idx < 8*K; idx += 256){
    int mm = idx / K, kk = idx - mm*K;
    As[mm][kk] = A[(size_t)(m0+mm)*lda + kk];
  }
  __syncthreads();
  float acc[8];
  if (biasOnM){
    #pragma unroll
    for (int mm=0; mm<8; ++mm) acc[mm] = bias[m0+mm];
  } else {
    float bs = bias[n];
    #pragma unroll
    for (int mm=0; mm<8; ++mm) acc[mm] = bs;
  }
  const float* bp = Bm + (size_t)n*ldb + boff;
  for (int k = 0; k < K; k += 4){
    float4 w = *(const float4*)(bp + k);
    #pragma unroll
    for (int mm = 0; mm < 8; ++mm)
      acc[mm] += As[mm][k]*w.x + As[mm][k+1]*w.y + As[mm][k+2]*w.z + As[mm][k+3]*w.w;
  }
  #pragma unroll
  for (int mm = 0; mm < 8; ++mm)
    C[(size_t)(m0+mm)*ldc + n] = acc[mm];
}

// ---------------- persistent bidirectional encoder (round-1, unchanged) ----------------
__global__ __launch_bounds__(512) void enc_persist(
    const float* __restrict__ Whh_f, const float* __restrict__ Whh_b,
    const float* __restrict__ Gx_f,  const float* __restrict__ Gx_b,
    float* __restrict__ h_cat, u32* ctrl, u32* hbuf)
{
  __shared__ __align__(16) u32 uni[32*268];
  __shared__ __align__(16) u32 wldsb[16*256];
  __shared__ float clds[128];
  __shared__ float exch[128];
  __shared__ int bail;

  const int tid = threadIdx.x, bid = blockIdx.x;
  const int dir = bid >> 7, dblk = bid & 127, d0 = dblk*4;
  const int b = tid & 31, grp = tid >> 5;
  const int dL = grp & 3, ks = grp >> 2;
  if (tid == 0) bail = 0;

  const float* Whh = dir ? Whh_b : Whh_f;
  const float* Gx  = dir ? Gx_b  : Gx_f;

  for (int idx = tid; idx < 16*256; idx += 512){
    int r = idx >> 8, p = idx & 255;
    int g = r >> 2, dl = r & 3;
    const float* wr = Whh + (size_t)(g*512 + d0 + dl)*512 + p*2;
    wldsb[idx] = pk2(wr[0], wr[1]);
  }

  u32* hb = hbuf + dir*2*8192;

  for (int t = 0; t < 64; ++t){
    int teff = dir ? (63 - t) : t;
    if (t > 0){
      const u32* src = hb + ((t&1)<<13);
      for (int idx = tid; idx < 8192; idx += 512)
        uni[(idx&31)*268 + (idx>>5)] = AT_LD32(src + idx);
    }
    __syncthreads();
    float a0=0.f,a1=0.f,a2=0.f,a3=0.f;
    if (t > 0){
      const u32* srow = uni + b*268 + ks*64;
      for (int c4 = 0; c4 < 16; ++c4){
        uint4 s4 = *(const uint4*)(srow + c4*4);
        float f0=lo16(s4.x),f1=hi16(s4.x),f2=lo16(s4.y),f3=hi16(s4.y);
        float f4=lo16(s4.z),f5=hi16(s4.z),f6=lo16(s4.w),f7=hi16(s4.w);
        int kp = ks*64 + c4*4;
        #pragma unroll
        for (int g = 0; g < 4; ++g){
          uint4 wq = *(const uint4*)(wldsb + (g*4+dL)*256 + kp);
          float s = f0*lo16(wq.x)+f1*hi16(wq.x)+f2*lo16(wq.y)+f3*hi16(wq.y)
                  + f4*lo16(wq.z)+f5*hi16(wq.z)+f6*lo16(wq.w)+f7*hi16(wq.w);
          if (g==0) a0+=s; else if (g==1) a1+=s; else if (g==2) a2+=s; else a3+=s;
        }
      }
    }
    __syncthreads();
    float* part = (float*)uni;
    { int base=(grp*32+b)*4; part[base]=a0; part[base+1]=a1; part[base+2]=a2; part[base+3]=a3; }
    __syncthreads();
    if (tid < 128){
      int bb = tid & 31, dl = tid >> 5;
      float r0=0.f,r1=0.f,r2=0.f,r3=0.f;
      #pragma unroll
      for (int kk = 0; kk < 4; ++kk){
        const float* p4 = part + (((kk<<2)|dl)*32 + bb)*4;
        r0+=p4[0]; r1+=p4[1]; r2+=p4[2]; r3+=p4[3];
      }
      const float* gx = Gx + ((size_t)teff*32 + bb)*2048;
      int d = d0 + dl;
      float gi=r0+gx[d], gf=r1+gx[512+d], gg=r2+gx[1024+d], go=r3+gx[1536+d];
      float c_ = (t==0) ? 0.f : clds[tid];
      float cn = sigf(gf)*c_ + sigf(gi)*tanhfast(gg);
      float hn = sigf(go)*tanhfast(cn);
      clds[tid] = cn;
      exch[tid] = hn;
      h_cat[((size_t)teff*32 + bb)*1024 + dir*512 + d] = hn;
    }
    __syncthreads();
    if (tid < 64){
      int bb = tid & 31, pp = tid >> 5;
      u32 u = pk2(exch[(pp*2)*32 + bb], exch[(pp*2+1)*32 + bb]);
      AT_ST32(hb + (((t+1)&1)<<13) + (dblk*2 + pp)*32 + bb, u);
    }
    gbar(ctrl, &bail);
  }
}

// ---------------- decoder v3: counter sync (scalar polls on cold lines) ----------------
union DSm {
  struct {
    u32   slds[8192];     // staged A (s or y_emb) [32][256] u32, XOR-swizzled in 16B granules
    float pre[2880];      // [c=80][36]  (c = q*16+dd)
    float ypl[2880];
    float sexch[512];
    int   tokl[32];
  } c;
  struct {
    u32   uni[8224];      // [32][257]
    float lred[4752];     // [144][33]
    u64   kred[512];      // [16][32]
  } l;
};

__device__ __forceinline__ void mfma_phase(const u32* __restrict__ sldsp,
    const u16* __restrict__ Bw, float* __restrict__ dst,
    int lane, int mtile, int nt0, int nB, int d0)
{
  const int mrow  = mtile*16 + (lane & 15);
  const int abase = mrow*256;
  const int asw   = (mrow & 7) << 2;
  const int ddc   = lane & 15;
  const size_t br0 = ((size_t)(nt0*512 + d0 + ddc)) * 512;
  const size_t br1 = ((size_t)((nt0+1)*512 + d0 + ddc)) * 512;
  const int kl = (lane >> 4) * 8;
  f32x4 acc0 = {0.f,0.f,0.f,0.f}, acc1 = {0.f,0.f,0.f,0.f};
  #pragma unroll
  for (int ks = 0; ks < 16; ++ks){
    const int dw = ks*16 + (lane>>4)*4;
    U4S8 a;  a.u  = *(const uint4*)&sldsp[abase + (dw ^ asw)];
    U4S8 b0; b0.u = *(const uint4*)(Bw + br0 + ks*32 + kl);
    acc0 = mfma16(a.s, b0.s, acc0);
    if (nB > 1){
      U4S8 b1; b1.u = *(const uint4*)(Bw + br1 + ks*32 + kl);
      acc1 = mfma16(a.s, b1.s, acc1);
    }
  }
  {
    float* p = &dst[(nt0*16 + ddc)*36 + mtile*16 + ((lane>>4)<<2)];
    *(f32x4*)p = acc0;
  }
  if (nB > 1){
    float* p = &dst[((nt0+1)*16 + ddc)*36 + mtile*16 + ((lane>>4)<<2)];
    *(f32x4*)p = acc1;
  }
}

__global__ __launch_bounds__(512) void dec_persist(
    const u16* __restrict__ Wsbf, const u16* __restrict__ Wxbf,
    const float* __restrict__ Wl, const float* __restrict__ bl,
    const float* __restrict__ emb, const float* __restrict__ hpartT,
    u32* stepcnt, u32* rowcnt, u32* done, u64* keys, u32* sbuf,
    float* __restrict__ out)
{
  __shared__ DSm sm;
  const int tid = threadIdx.x, bid = blockIdx.x;
  const int lane = tid & 63;

  if (bid < 32){
    // ================= cell blocks =================
    const int w = tid >> 6, mtile = w & 1, ng = w >> 1;
    const int nt0 = (ng == 0) ? 0 : (ng + 1);
    const int nB  = (ng == 0) ? 2 : 1;
    const int dd = tid >> 5, b = tid & 31;
    const int d0 = bid * 16;
    float creg = 0.f;

    for (int i = 0; i < 64; ++i){
      const u32 base = i*64;
      if (i == 0){
        for (int idx = tid; idx < 2880; idx += 512) sm.c.ypl[idx] = 0.f;
        __syncthreads();
      } else {
        if (tid == 0){
          long cc = 0;
          while (AT_LD32(done + (i-1)) < 224u){
            __builtin_amdgcn_s_sleep(4);
            if (++cc > (1L<<22)) break;
          }
        }
        __syncthreads();
        if (tid < 32){
          u64 kk = AT_LD64(keys + (size_t)(i-1)*32 + tid);
          int tk = (int)(~(u32)kk);
          tk = tk < 0 ? 0 : (tk > 31999 ? 31999 : tk);
          sm.c.tokl[tid] = tk;
        }
        __syncthreads();
        for (int idx = tid; idx < 8192; idx += 512){
          int bb = idx >> 8, dp = idx & 255;
          const float* er = emb + (size_t)sm.c.tokl[bb]*512 + dp*2;
          sm.c.slds[bb*256 + (dp ^ ((bb&7)<<2))] = pk2(er[0], er[1]);
        }
        __syncthreads();
        mfma_phase(sm.c.slds, Wxbf, sm.c.ypl, lane, mtile, nt0, nB, d0);
        __syncthreads();
      }
      creg = 0.f;

      for (int j = 0; j < 64; ++j){
        const u32 g = base + j + 1;   // state produced this step
        float hp[5];
        {
          const float* hb = hpartT + (size_t)(d0 + dd)*2048 + j*32 + b;
          #pragma unroll
          for (int q = 0; q < 5; ++q) hp[q] = hb[(size_t)q*512*2048];
        }
        if (j > 0){
          if (tid == 0){
            const u32 tgt = 32u*(base + j);
            long cc = 0;
            while (AT_LD32(stepcnt) < tgt){
              __builtin_amdgcn_s_sleep(1);
              if (++cc > (1L<<22)) break;
            }
          }
          __syncthreads();
          const u64* sb64 = (const u64*)(sbuf + ((size_t)((g-1) & 1) << 13));
          u64* sl64 = (u64*)sm.c.slds;
          for (int idx = tid; idx < 4096; idx += 512){
            int bb = idx >> 7, dp0 = (idx & 127) << 1;
            int sw = (bb & 7) << 2;
            sl64[bb*128 + ((dp0 ^ sw) >> 1)] = AT_LD64(sb64 + idx);
          }
          __syncthreads();
          mfma_phase(sm.c.slds, Wsbf, sm.c.pre, lane, mtile, nt0, nB, d0);
        }
        __syncthreads();
        // gates: one thread per (dd, b)
        {
          float pv[5];
          #pragma unroll
          for (int q = 0; q < 5; ++q){
            float x = sm.c.ypl[(q*16 + dd)*36 + b] + hp[q];
            if (j > 0) x += sm.c.pre[(q*16 + dd)*36 + b];
            pv[q] = x;
          }
          float gi = sigf(pv[0]), gf = sigf(pv[1]), go = sigf(pv[2]), gl = sigf(pv[3]);
          float cn = gf * (gl * creg) + gi * tanhfast(pv[4]);
          creg = cn;
          sm.c.sexch[dd*32 + b] = go * tanhfast(cn);
        }
        __syncthreads();
        if (tid < 128){
          int u = tid >> 5, bb = tid & 31;
          int dd0 = u*4;
          u32 lo = pk2(sm.c.sexch[dd0*32 + bb],     sm.c.sexch[(dd0+1)*32 + bb]);
          u32 hi = pk2(sm.c.sexch[(dd0+2)*32 + bb], sm.c.sexch[(dd0+3)*32 + bb]);
          u64 val = (u64)lo | ((u64)hi << 32);
          u64* dst = (u64*)(sbuf + ((size_t)(g & 1) << 13));
          AT_ST64(dst + bb*128 + bid*4 + u, val);
        }
        asm volatile("s_waitcnt vmcnt(0)" ::: "memory");
        __syncthreads();
        if (tid == 0) AT_ADD32(stepcnt, 1u);
      }
      if (tid == 0) AT_ADD32(rowcnt + i*16, 1u);
    }
  } else {
    // ================= logits blocks =================
    const int lb = bid - 32;
    const int v0 = lb * 143;
    int nv = 32000 - v0; if (nv > 143) nv = 143;
    const int grp = tid >> 5, b = tid & 31;

    for (int i = 0; i < 64; ++i){
      if (tid == 0){
        long cc = 0;
        while (AT_LD32(rowcnt + i*16) < 32u){
          __builtin_amdgcn_s_sleep(16);
          if (++cc > (1L<<22)) break;
        }
      }
      __syncthreads();
      for (int idx = tid; idx < 8192; idx += 512){
        int bb = idx >> 8, dp = idx & 255;
        sm.l.uni[bb*257 + dp] = AT_LD32(sbuf + idx);   // s_J parity 0
      }
      __syncthreads();
      float acc[9];
      #pragma unroll
      for (int t = 0; t < 9; ++t){
        int vt = grp + 16*t;
        acc[t] = (vt < nv) ? bl[v0 + vt] : -1e30f;
      }
      const u32* srow = sm.l.uni + b*257;
      for (int pp = 0; pp < 128; ++pp){
        u32 u0 = srow[pp*2], u1 = srow[pp*2 + 1];
        float f0 = lo16(u0), f1 = hi16(u0), f2 = lo16(u1), f3 = hi16(u1);
        #pragma unroll
        for (int t = 0; t < 9; ++t){
          int vt = grp + 16*t;
          if (vt < nv){
            const float4 w4 = *(const float4*)(Wl + (size_t)(v0 + vt)*512 + pp*4);
            acc[t] += f0*w4.x + f1*w4.y + f2*w4.z + f3*w4.w;
          }
        }
      }
      u64 best = 0;
      #pragma unroll
      for (int t = 0; t < 9; ++t){
        int vt = grp + 16*t;
        if (vt < nv){
          sm.l.lred[vt*33 + b] = acc[t];
          u32 su = __float_as_uint(acc[t]);
          su = (su >> 31) ? ~su : (su | 0x80000000u);
          u64 key = ((u64)su << 32) | (u32)(~(u32)(v0 + vt));
          if (key > best) best = key;
        }
      }
      sm.l.kred[grp*32 + b] = best;
      __syncthreads();
      const size_t obase = ((size_t)i*32)*32000 + v0;
      for (int bb = 0; bb < 32; ++bb){
        for (int v = tid; v < nv; v += 512)
          out[obase + (size_t)bb*32000 + v] = sm.l.lred[v*33 + bb];
      }
      if (tid < 32){
        u64 m = 0;
        #pragma unroll
        for (int q2 = 0; q2 < 16; ++q2){ u64 x = sm.l.kred[q2*32 + tid]; if (x > m) m = x; }
        AT_MAX64(keys + (size_t)i*32 + tid, m);
      }
      asm volatile("s_waitcnt vmcnt(0)" ::: "memory");
      __syncthreads();
      if (tid == 0) AT_ADD32(done + i, 1u);
    }
  }
}

__global__ __launch_bounds__(256) void softmax_k(float* __restrict__ out){
  size_t row = blockIdx.x;
  float* p = out + row*32000;
  __shared__ float red[256];
  float s = 0.f;
  for (int v = threadIdx.x; v < 32000; v += 256) s += __expf(p[v]);
  red[threadIdx.x] = s;
  __syncthreads();
  for (int off = 128; off > 0; off >>= 1){
    if (threadIdx.x < off) red[threadIdx.x] += red[threadIdx.x+off];
    __syncthreads();
  }
  float Z = red[0];
  for (int v = threadIdx.x; v < 32000; v += 256) p[v] = __expf(p[v]) / Z;
}

extern "C" void kernel_launch(void* const* d_in, const int* in_sizes, int n_in,
                              void* d_out, int out_size, void* d_ws, size_t ws_size,
                              hipStream_t stream)
{
  const int*   x    = (const int*)d_in[0];
  const float* emb  = (const float*)d_in[2];
  const float* Wihf = (const float*)d_in[3];
  const float* Whhf = (const float*)d_in[4];
  const float* bf   = (const float*)d_in[5];
  const float* Wihb = (const float*)d_in[6];
  const float* Whhb = (const float*)d_in[7];
  const float* bb   = (const float*)d_in[8];
  const float* Wx   = (const float*)d_in[9];
  const float* Ws   = (const float*)d_in[10];
  const float* bc   = (const float*)d_in[11];
  const float* Wl   = (const float*)d_in[12];
  const float* bl   = (const float*)d_in[13];

  char* ws = (char*)d_ws;
  u32* ctrl    = (u32*)ws;                      // 1280 B (gbar, encoder)
  u32* stepcnt = (u32*)(ws + 1536);             // 1 u32 (own line)
  u32* done    = (u32*)(ws + 2048);             // 64 u32
  u32* rowcnt  = (u32*)(ws + 2560);             // 64 rows x 16 u32 (line apart)
  u64* keys    = (u64*)(ws + 8192);             // 64x32 u64 = 16 KB -> 24576
  u32* sbuf    = (u32*)(ws + 24576);            // 2x8192 u32 = 64 KB -> 90112
  u32* hbuf    = (u32*)(ws + 90112);            // 128 KB -> 221184
  float* emb_x = (float*)(ws + 221184);         // 4 MB   -> 4415488
  float* h_cat = (float*)(ws + 4415488);        // 8 MB   -> 12804096
  float* GxfP  = (float*)(ws + 12804096);       // 16 MB  -> 29581312
  float* GxbP  = (float*)(ws + 29581312);       // 16 MB  -> 46358528
  float* hpartT = GxfP;                         // 2560x2048 f32 = 21 MB (Gx dead after encoder)
  u16* Wsbf = (u16*)emb_x;                      // 2.6 MB (emb_x dead after Gx gemms)
  u16* Wxbf = (u16*)h_cat;                      // 2.6 MB (h_cat dead after hpartT gemm)

  hipLaunchKernelGGL(init_ctrl, dim3(1), dim3(512), 0, stream, (u32*)ws);
  hipLaunchKernelGGL(embed_k, dim3(4096), dim3(256), 0, stream, x, emb, emb_x);
  hipLaunchKernelGGL(gemm_f32, dim3(8,256), dim3(256), 0, stream,
                     emb_x, 512, Wihf, 512, 0, bf, 0, GxfP, 2048, 512);
  hipLaunchKernelGGL(gemm_f32, dim3(8,256), dim3(256), 0, stream,
                     emb_x, 512, Wihb, 512, 0, bb, 0, GxbP, 2048, 512);
  hipLaunchKernelGGL(enc_persist, dim3(256), dim3(512), 0, stream,
                     Whhf, Whhb, GxfP, GxbP, h_cat, ctrl, hbuf);
  // hpartT[c][t*32+b] = bc[c] + sum_k Wx[c*1536+512+k] * h_cat[(t*32+b)*1024+k]
  hipLaunchKernelGGL(gemm_f32, dim3(8,320), dim3(256), 0, stream,
                     Wx + 512, 1536, h_cat, 1024, 0, bc, 1, hpartT, 2048, 1024);
  hipLaunchKernelGGL(conv_bf16_k, dim3(2560), dim3(256), 0, stream, Ws, 1024, Wsbf);
  hipLaunchKernelGGL(conv_bf16_k, dim3(2560), dim3(256), 0, stream, Wx, 1536, Wxbf);
  hipLaunchKernelGGL(dec_persist, dim3(256), dim3(512), 0, stream,
                     Wsbf, Wxbf, Wl, bl, emb, hpartT, stepcnt, rowcnt, done, keys, sbuf,
                     (float*)d_out);
  hipLaunchKernelGGL(softmax_k, dim3(2048), dim3(256), 0, stream, (float*)d_out);
}